// Round 11
// baseline (160.731 us; speedup 1.0000x reference)
//
#include <hip/hip_runtime.h>
#include <hip/hip_bf16.h>

#define NN 256
#define NH 8
#define NB 4
#define NPOS (NB * NN * NN)   // 262144 positions (b,n,m)

typedef float f32x4 __attribute__((ext_vector_type(4)));

// ---------------------------------------------------------------------------
// Kernel 1: attn[p][h] = sigmoid( dot(concat(q[p],k[p]), W[:,h]) + b[h] )
// R10 diagnosis: VGPR=76 is impossible for the intended schedule (needs
// W 64 + dbuf 64 + acc 32 + addr ~12 = ~172) -- ONE reg over the ~170 cap
// that __launch_bounds__(256,3) imposes. Allocator cascade: spills asm load
// outputs right after def (spill-store = implicit vmcnt drain -> prefetch
// dead) and/or spills W (scratch reloads inside every posval). Fix:
// (1) __launch_bounds__(256,2) -> cap 256, ~86 regs headroom;
// (2) sched_barrier(0) BETWEEN posvals -> no 4-way interleave, acc pressure
// 32->8. Loads stay inline-asm global_load_dwordx4 with counted vmcnt(8).
// ---------------------------------------------------------------------------
__device__ __forceinline__ float posval(
    const f32x4 qv, const f32x4 kv,
    const f32x4* __restrict__ wqA, const f32x4* __restrict__ wqB,
    const f32x4* __restrict__ wkA, const f32x4* __restrict__ wkB,
    const int c)
{
    f32x4 accA, accB;
    accA  = wqA[0] * qv.x;  accB  = wqB[0] * qv.x;
    accA += wqA[1] * qv.y;  accB += wqB[1] * qv.y;
    accA += wqA[2] * qv.z;  accB += wqB[2] * qv.z;
    accA += wqA[3] * qv.w;  accB += wqB[3] * qv.w;
    accA += wkA[0] * kv.x;  accB += wkB[0] * kv.x;
    accA += wkA[1] * kv.y;  accB += wkB[1] * kv.y;
    accA += wkA[2] * kv.z;  accB += wkB[2] * kv.z;
    accA += wkA[3] * kv.w;  accB += wkB[3] * kv.w;

#pragma unroll
    for (int d = 1; d <= 4; d <<= 1) {
        accA.x += __shfl_xor(accA.x, d);
        accA.y += __shfl_xor(accA.y, d);
        accA.z += __shfl_xor(accA.z, d);
        accA.w += __shfl_xor(accA.w, d);
        accB.x += __shfl_xor(accB.x, d);
        accB.y += __shfl_xor(accB.y, d);
        accB.z += __shfl_xor(accB.z, d);
        accB.w += __shfl_xor(accB.w, d);
    }
    float my = accA.x;
    my = (c == 1) ? accA.y : my;
    my = (c == 2) ? accA.z : my;
    my = (c == 3) ? accA.w : my;
    my = (c == 4) ? accB.x : my;
    my = (c == 5) ? accB.y : my;
    my = (c == 6) ? accB.z : my;
    my = (c == 7) ? accB.w : my;
    my += __shfl_xor(my, 8);
    my += __shfl_xor(my, 16);
    my += __shfl_xor(my, 32);
    return my;
}

// 4 position-rows (1KB apart) from one base pointer, forced by asm.
#define GLOAD4(d, voff, base)                                               \
    asm volatile("global_load_dwordx4 %0, %4, %5 offset:0\n\t"              \
                 "global_load_dwordx4 %1, %4, %5 offset:1024\n\t"           \
                 "global_load_dwordx4 %2, %4, %5 offset:2048\n\t"           \
                 "global_load_dwordx4 %3, %4, %5 offset:3072"               \
                 : "=&v"(d[0]), "=&v"(d[1]), "=&v"(d[2]), "=&v"(d[3])       \
                 : "v"(voff), "s"(base) : "memory")

#define WAITV(N)                                                            \
    asm volatile("s_waitcnt vmcnt(" #N ")" ::: "memory");                   \
    __builtin_amdgcn_sched_barrier(0)

#define COMPUTEB(sq, sk, pb)                                                \
    {                                                                       \
        const float m0 = posval(sq[0], sk[0], wqA, wqB, wkA, wkB, c);       \
        __builtin_amdgcn_sched_barrier(0);                                  \
        const float m1 = posval(sq[1], sk[1], wqA, wqB, wkA, wkB, c);       \
        __builtin_amdgcn_sched_barrier(0);                                  \
        const float m2 = posval(sq[2], sk[2], wqA, wqB, wkA, wkB, c);       \
        __builtin_amdgcn_sched_barrier(0);                                  \
        const float m3 = posval(sq[3], sk[3], wqA, wqB, wkA, wkB, c);       \
        __builtin_amdgcn_sched_barrier(0);                                  \
        float v = m0;                                                       \
        v = (g2 == 1) ? m1 : v;                                             \
        v = (g2 == 2) ? m2 : v;                                             \
        v = (g2 == 3) ? m3 : v;                                             \
        v = 1.f / (1.f + __expf(-(v + bb)));                                \
        if (lane < 32) attn[(size_t)(pb) * NH + lane] = v;                  \
    }

__global__ __launch_bounds__(256, 2) void attn_kernel(
    const float* __restrict__ q, const float* __restrict__ k,
    const float* __restrict__ W, const float* __restrict__ bias,
    float* __restrict__ attn)
{
    const int tid = threadIdx.x;
    const int lane = tid & 63;
    const int c = lane & 7;
    const int g2 = (lane >> 3) & 3;    // batch-position select for packed store

    f32x4 wqA[4], wqB[4], wkA[4], wkB[4];
#pragma unroll
    for (int cc = 0; cc < 4; ++cc) {
        const float* wr = W + (size_t)(4 * lane + cc) * NH;
        wqA[cc] = *(const f32x4*)(wr);
        wqB[cc] = *(const f32x4*)(wr + 4);
        const float* wr2 = W + (size_t)(256 + 4 * lane + cc) * NH;
        wkA[cc] = *(const f32x4*)(wr2);
        wkB[cc] = *(const f32x4*)(wr2 + 4);
    }
#pragma unroll
    for (int cc = 0; cc < 4; ++cc) {
        asm volatile("" : "+v"(wqA[cc]), "+v"(wqB[cc]),
                          "+v"(wkA[cc]), "+v"(wkB[cc]));
    }
    const float bb = bias[c];

    const int gwave = blockIdx.x * (blockDim.x >> 6) + (tid >> 6);

    // 8192 waves x 32 contiguous positions each = NPOS exactly
    int pb = gwave * 32;
    // byte voffset: position-row base + lane*16 (1KB rows)
    unsigned int voff = (unsigned int)pb * 1024u + (unsigned int)lane * 16u;

    f32x4 qA[4], kA[4], qB[4], kB[4];
    GLOAD4(qA, voff, q);       // batch 0 -> A buffers (8 loads in flight)
    GLOAD4(kA, voff, k);

#pragma unroll
    for (int b = 0; b < 8; ++b) {
        const unsigned int vnext = voff + 4096u;
        if ((b & 1) == 0) {
            if (b < 7) {       // issue batch b+1 -> B buffers
                GLOAD4(qB, vnext, q);
                GLOAD4(kB, vnext, k);
                WAITV(8);      // batch b (A) resident; B's 8 stay in flight
            } else {
                WAITV(0);
            }
            COMPUTEB(qA, kA, pb);
        } else {
            if (b < 7) {       // issue batch b+1 -> A buffers
                GLOAD4(qA, vnext, q);
                GLOAD4(kA, vnext, k);
                WAITV(8);
            } else {
                WAITV(0);
            }
            COMPUTEB(qB, kB, pb);
        }
        __builtin_amdgcn_sched_barrier(0);
        voff = vnext;
        pb += 4;
    }
}

// ---------------------------------------------------------------------------
// Kernel 2: dim2_mask union of top-k / bottom-k indices (exact rank count,
// matches jax.lax.top_k stable tie-breaking). Register-accumulated selection,
// ballot + 2 atomicOr per wave; 64 publisher blocks seed the mask per-task;
// everyone early-exits on full mask via volatile loads (monotonic bits =>
// stale reads are safe).
// ---------------------------------------------------------------------------
__global__ __launch_bounds__(256) void topk_kernel(
    const float* __restrict__ attn, const float* __restrict__ m1,
    const float* __restrict__ m2, unsigned int* __restrict__ maskw)
{
    __shared__ __align__(16) float a[NN];
    __shared__ int snotfull;
    const int tid = threadIdx.x;
    const int T = 2 * NB * NN * NH;   // 16384 tasks
    const bool publisher = (blockIdx.x < 64);
    const volatile unsigned int* vmask = maskw;
    bool selAcc = false;
    bool broke = false;

    for (int t = blockIdx.x; t < T; t += gridDim.x) {
        if (t != (int)blockIdx.x) {
            if (tid == 0) snotfull = 0;
            __syncthreads();
            if (tid < 8 && vmask[tid] != 0xFFFFFFFFu) snotfull = 1;
            __syncthreads();
            if (!snotfull) { broke = true; break; }
        }

        const int variant = t >> 13;
        const int r = t & 8191;
        const int h = r & 7;
        const int n = (r >> 3) & 255;
        const int b = r >> 11;
        const size_t rowBase = ((size_t)(b * NN + n)) * NN;
        const float* mk = variant ? m2 : m1;
        const int kt = variant ? 128 : 64;
        const int kb = 64;

        a[tid] = attn[(rowBase + tid) * NH + h] * mk[rowBase + tid];
        __syncthreads();

        const float av = a[tid];
        int gt = 0, lt = 0, el = 0;
#pragma unroll 8
        for (int u4 = 0; u4 < NN / 4; ++u4) {
            const f32x4 w = *reinterpret_cast<const f32x4*>(&a[u4 * 4]);
            const int u = u4 * 4;
            gt += (w.x > av) + (w.y > av) + (w.z > av) + (w.w > av);
            lt += (w.x < av) + (w.y < av) + (w.z < av) + (w.w < av);
            el += ((w.x == av) & (u + 0 < tid)) + ((w.y == av) & (u + 1 < tid))
                + ((w.z == av) & (u + 2 < tid)) + ((w.w == av) & (u + 3 < tid));
        }
        const bool sel = ((gt + el) < kt) || ((lt + el) < kb);
        selAcc |= sel;

        if (publisher) {
            const unsigned long long bal = __ballot(sel);
            if ((tid & 63) == 0) {
                const int w = tid >> 6;
                atomicOr(&maskw[w * 2 + 0], (unsigned int)(bal & 0xFFFFFFFFull));
                atomicOr(&maskw[w * 2 + 1], (unsigned int)(bal >> 32));
            }
        }
        __syncthreads();
    }

    if (!broke && !publisher) {
        const unsigned long long bal = __ballot(selAcc);
        if ((tid & 63) == 0) {
            const int w = tid >> 6;
            atomicOr(&maskw[w * 2 + 0], (unsigned int)(bal & 0xFFFFFFFFull));
            atomicOr(&maskw[w * 2 + 1], (unsigned int)(bal >> 32));
        }
    }
}

// ---------------------------------------------------------------------------
// Kernel 3: out *= (m1+m2) * dim2_mask[m], in place, float4 over H.
// ---------------------------------------------------------------------------
__global__ __launch_bounds__(256) void finalize_kernel(
    float* __restrict__ out, const float* __restrict__ m1,
    const float* __restrict__ m2, const unsigned int* __restrict__ maskw)
{
    const int total = NPOS * 2;       // float4 units (H=8 -> 2 per position)
    for (int i4 = blockIdx.x * blockDim.x + threadIdx.x; i4 < total;
         i4 += gridDim.x * blockDim.x) {
        const int m = (i4 >> 1) & 255;
        const int bn = i4 >> 9;
        const float bit = ((maskw[m >> 5] >> (m & 31)) & 1u) ? 1.f : 0.f;
        const size_t mi = (size_t)bn * NN + m;
        const float scale = (m1[mi] + m2[mi]) * bit;
        f32x4 v = reinterpret_cast<f32x4*>(out)[i4];
        v.x *= scale; v.y *= scale; v.z *= scale; v.w *= scale;
        reinterpret_cast<f32x4*>(out)[i4] = v;
    }
}

__global__ void init_kernel(unsigned int* maskw)
{
    if (threadIdx.x < 8) maskw[threadIdx.x] = 0u;
}

extern "C" void kernel_launch(void* const* d_in, const int* in_sizes, int n_in,
                              void* d_out, int out_size, void* d_ws, size_t ws_size,
                              hipStream_t stream) {
    const float* q    = (const float*)d_in[0];
    const float* kk   = (const float*)d_in[1];
    const float* m1   = (const float*)d_in[2];
    const float* m2   = (const float*)d_in[3];
    const float* W    = (const float*)d_in[4];
    const float* bias = (const float*)d_in[5];
    float* out = (float*)d_out;

    unsigned int* maskw = (unsigned int*)d_ws;

    hipLaunchKernelGGL(init_kernel, dim3(1), dim3(64), 0, stream, maskw);
    // 2048 blocks * 4 waves = 8192 waves * 32 positions = NPOS exactly
    hipLaunchKernelGGL(attn_kernel, dim3(2048), dim3(256), 0, stream,
                       q, kk, W, bias, out);
    hipLaunchKernelGGL(topk_kernel, dim3(1024), dim3(256), 0, stream,
                       out, m1, m2, maskw);
    hipLaunchKernelGGL(finalize_kernel, dim3(2048), dim3(256), 0, stream,
                       out, m1, m2, maskw);
}

// Round 12
// 146.239 us; speedup vs baseline: 1.0991x; 1.0991x over previous
//
#include <hip/hip_runtime.h>
#include <hip/hip_bf16.h>

#define NN 256
#define NH 8
#define NB 4
#define NPOS (NB * NN * NN)   // 262144 positions (b,n,m)

typedef float f32x4 __attribute__((ext_vector_type(4)));
typedef short bf16x8 __attribute__((ext_vector_type(8)));

static __device__ __forceinline__ short f2bf(float f) {
    __hip_bfloat16 h = __float2bfloat16(f);
    union { __hip_bfloat16 b; short s; } u; u.b = h; return u.s;
}

// ---------------------------------------------------------------------------
// Kernel 1 (MFMA): attn[p][h] = sigmoid( [NPOS x 512] @ W[512 x 8] + b )
// One wave = 16 positions, 16 x mfma_f32_16x16x32_bf16 over K=512 (8 q-chunks
// + 8 k-chunks). A-frag: lane supplies A[row=l&15][k=(l>>4)*8+j] -- two
// dwordx4 per step, 32 independent loads/tile (32KB in flight; > BW*latency
// even at 1 wave/CU). B-frag (W): built once per wave from an 8KB LDS
// transpose; constant across the K-loop. C: col=l&15, row=(l>>4)*4+i (m89).
// VALU/pos ~10 (bf16 cvt only) vs ~100 in the VALU formulation.
// ---------------------------------------------------------------------------
__global__ __launch_bounds__(256, 2) void attn_kernel(
    const float* __restrict__ q, const float* __restrict__ k,
    const float* __restrict__ W, const float* __restrict__ bias,
    float* __restrict__ attn)
{
    __shared__ unsigned short wt[8][512];   // 8KB: W^T as bf16, wt[col][row]
    const int tid = threadIdx.x;
    const int lane = tid & 63;
    const int wid = tid >> 6;

    // one-time cooperative W transpose: thread t handles rows 2t, 2t+1
    {
        const int r0 = tid * 2;
#pragma unroll
        for (int rr = 0; rr < 2; ++rr) {
            const int r = r0 + rr;
            f32x4 a = *(const f32x4*)(W + (size_t)r * NH);
            f32x4 b = *(const f32x4*)(W + (size_t)r * NH + 4);
            wt[0][r] = (unsigned short)f2bf(a.x);
            wt[1][r] = (unsigned short)f2bf(a.y);
            wt[2][r] = (unsigned short)f2bf(a.z);
            wt[3][r] = (unsigned short)f2bf(a.w);
            wt[4][r] = (unsigned short)f2bf(b.x);
            wt[5][r] = (unsigned short)f2bf(b.y);
            wt[6][r] = (unsigned short)f2bf(b.z);
            wt[7][r] = (unsigned short)f2bf(b.w);
        }
    }
    __syncthreads();

    const int r15 = lane & 15;          // A row / B-C col index
    const int kg  = lane >> 4;          // k-group 0..3

    // B fragments (W^T) for all 16 K-steps: lane holds B[k=kg*8+j][col=r15].
    // wt offset = r15*1024 + (s*32+kg*8)*2 bytes -- 16B aligned ds_read_b128.
    bf16x8 wfrag[16];
#pragma unroll
    for (int s = 0; s < 16; ++s) {
        if (r15 < 8) {
            wfrag[s] = *(const bf16x8*)(&wt[r15][s * 32 + kg * 8]);
        } else {
#pragma unroll
            for (int j = 0; j < 8; ++j) wfrag[s][j] = 0;
        }
    }
#pragma unroll
    for (int s = 0; s < 16; ++s)
        asm volatile("" : "+v"(wfrag[s]));   // keep resident, no remat

    const int gwave = blockIdx.x * 4 + wid;  // 0..16383
    const int p0 = gwave * 16;               // 16 positions per wave

    const float* qrow = q + (size_t)(p0 + r15) * 256 + kg * 8;
    const float* krow = k + (size_t)(p0 + r15) * 256 + kg * 8;

    // load + convert all 16 A-fragments (32 independent dwordx4)
    bf16x8 afrag[16];
#pragma unroll
    for (int s = 0; s < 8; ++s) {
        f32x4 lo = *(const f32x4*)(qrow + s * 32);
        f32x4 hi = *(const f32x4*)(qrow + s * 32 + 4);
        afrag[s][0] = f2bf(lo.x); afrag[s][1] = f2bf(lo.y);
        afrag[s][2] = f2bf(lo.z); afrag[s][3] = f2bf(lo.w);
        afrag[s][4] = f2bf(hi.x); afrag[s][5] = f2bf(hi.y);
        afrag[s][6] = f2bf(hi.z); afrag[s][7] = f2bf(hi.w);
    }
#pragma unroll
    for (int s = 0; s < 8; ++s) {
        f32x4 lo = *(const f32x4*)(krow + s * 32);
        f32x4 hi = *(const f32x4*)(krow + s * 32 + 4);
        afrag[8 + s][0] = f2bf(lo.x); afrag[8 + s][1] = f2bf(lo.y);
        afrag[8 + s][2] = f2bf(lo.z); afrag[8 + s][3] = f2bf(lo.w);
        afrag[8 + s][4] = f2bf(hi.x); afrag[8 + s][5] = f2bf(hi.y);
        afrag[8 + s][6] = f2bf(hi.z); afrag[8 + s][7] = f2bf(hi.w);
    }

    f32x4 acc = {0.f, 0.f, 0.f, 0.f};
#pragma unroll
    for (int s = 0; s < 16; ++s)
        acc = __builtin_amdgcn_mfma_f32_16x16x32_bf16(afrag[s], wfrag[s], acc,
                                                      0, 0, 0);

    // epilogue: C[row=kg*4+i][col=r15]; cols 0..7 valid
    if (r15 < 8) {
        const float bb = bias[r15];
#pragma unroll
        for (int i = 0; i < 4; ++i) {
            const int pos = p0 + kg * 4 + i;
            const float s = 1.f / (1.f + __expf(-(acc[i] + bb)));
            attn[(size_t)pos * NH + r15] = s;
        }
    }
}

// ---------------------------------------------------------------------------
// Kernel 2: dim2_mask union of top-k / bottom-k indices (exact rank count,
// matches jax.lax.top_k stable tie-breaking). Register-accumulated selection,
// ballot + 2 atomicOr per wave; 64 publisher blocks seed the mask per-task;
// everyone early-exits on full mask via volatile loads (monotonic bits =>
// stale reads are safe).
// ---------------------------------------------------------------------------
__global__ __launch_bounds__(256) void topk_kernel(
    const float* __restrict__ attn, const float* __restrict__ m1,
    const float* __restrict__ m2, unsigned int* __restrict__ maskw)
{
    __shared__ __align__(16) float a[NN];
    __shared__ int snotfull;
    const int tid = threadIdx.x;
    const int T = 2 * NB * NN * NH;   // 16384 tasks
    const bool publisher = (blockIdx.x < 64);
    const volatile unsigned int* vmask = maskw;
    bool selAcc = false;
    bool broke = false;

    for (int t = blockIdx.x; t < T; t += gridDim.x) {
        if (t != (int)blockIdx.x) {
            if (tid == 0) snotfull = 0;
            __syncthreads();
            if (tid < 8 && vmask[tid] != 0xFFFFFFFFu) snotfull = 1;
            __syncthreads();
            if (!snotfull) { broke = true; break; }
        }

        const int variant = t >> 13;
        const int r = t & 8191;
        const int h = r & 7;
        const int n = (r >> 3) & 255;
        const int b = r >> 11;
        const size_t rowBase = ((size_t)(b * NN + n)) * NN;
        const float* mk = variant ? m2 : m1;
        const int kt = variant ? 128 : 64;
        const int kb = 64;

        a[tid] = attn[(rowBase + tid) * NH + h] * mk[rowBase + tid];
        __syncthreads();

        const float av = a[tid];
        int gt = 0, lt = 0, el = 0;
#pragma unroll 8
        for (int u4 = 0; u4 < NN / 4; ++u4) {
            const f32x4 w = *reinterpret_cast<const f32x4*>(&a[u4 * 4]);
            const int u = u4 * 4;
            gt += (w.x > av) + (w.y > av) + (w.z > av) + (w.w > av);
            lt += (w.x < av) + (w.y < av) + (w.z < av) + (w.w < av);
            el += ((w.x == av) & (u + 0 < tid)) + ((w.y == av) & (u + 1 < tid))
                + ((w.z == av) & (u + 2 < tid)) + ((w.w == av) & (u + 3 < tid));
        }
        const bool sel = ((gt + el) < kt) || ((lt + el) < kb);
        selAcc |= sel;

        if (publisher) {
            const unsigned long long bal = __ballot(sel);
            if ((tid & 63) == 0) {
                const int w = tid >> 6;
                atomicOr(&maskw[w * 2 + 0], (unsigned int)(bal & 0xFFFFFFFFull));
                atomicOr(&maskw[w * 2 + 1], (unsigned int)(bal >> 32));
            }
        }
        __syncthreads();
    }

    if (!broke && !publisher) {
        const unsigned long long bal = __ballot(selAcc);
        if ((tid & 63) == 0) {
            const int w = tid >> 6;
            atomicOr(&maskw[w * 2 + 0], (unsigned int)(bal & 0xFFFFFFFFull));
            atomicOr(&maskw[w * 2 + 1], (unsigned int)(bal >> 32));
        }
    }
}

// ---------------------------------------------------------------------------
// Kernel 3: out *= (m1+m2) * dim2_mask[m], in place, float4 over H.
// ---------------------------------------------------------------------------
__global__ __launch_bounds__(256) void finalize_kernel(
    float* __restrict__ out, const float* __restrict__ m1,
    const float* __restrict__ m2, const unsigned int* __restrict__ maskw)
{
    const int total = NPOS * 2;       // float4 units (H=8 -> 2 per position)
    for (int i4 = blockIdx.x * blockDim.x + threadIdx.x; i4 < total;
         i4 += gridDim.x * blockDim.x) {
        const int m = (i4 >> 1) & 255;
        const int bn = i4 >> 9;
        const float bit = ((maskw[m >> 5] >> (m & 31)) & 1u) ? 1.f : 0.f;
        const size_t mi = (size_t)bn * NN + m;
        const float scale = (m1[mi] + m2[mi]) * bit;
        f32x4 v = reinterpret_cast<f32x4*>(out)[i4];
        v.x *= scale; v.y *= scale; v.z *= scale; v.w *= scale;
        reinterpret_cast<f32x4*>(out)[i4] = v;
    }
}

__global__ void init_kernel(unsigned int* maskw)
{
    if (threadIdx.x < 8) maskw[threadIdx.x] = 0u;
}

extern "C" void kernel_launch(void* const* d_in, const int* in_sizes, int n_in,
                              void* d_out, int out_size, void* d_ws, size_t ws_size,
                              hipStream_t stream) {
    const float* q    = (const float*)d_in[0];
    const float* kk   = (const float*)d_in[1];
    const float* m1   = (const float*)d_in[2];
    const float* m2   = (const float*)d_in[3];
    const float* W    = (const float*)d_in[4];
    const float* bias = (const float*)d_in[5];
    float* out = (float*)d_out;

    unsigned int* maskw = (unsigned int*)d_ws;

    hipLaunchKernelGGL(init_kernel, dim3(1), dim3(64), 0, stream, maskw);
    // 4096 blocks * 4 waves = 16384 waves; 16 positions each = NPOS exactly
    hipLaunchKernelGGL(attn_kernel, dim3(4096), dim3(256), 0, stream,
                       q, kk, W, bias, out);
    hipLaunchKernelGGL(topk_kernel, dim3(1024), dim3(256), 0, stream,
                       out, m1, m2, maskw);
    hipLaunchKernelGGL(finalize_kernel, dim3(2048), dim3(256), 0, stream,
                       out, m1, m2, maskw);
}